// Round 11
// baseline (1176.892 us; speedup 1.0000x reference)
//
#include <hip/hip_runtime.h>

#define HH 1024
#define WW 1024
#define BH 64
#define NSTEP 22          // 6 pipeline-fill + 16 emit steps (4 rows each)
#define DTC (0.1f/3.0f)

// Full-width row pipeline, 4 rows per step, parity double-buffered (1 barrier/step).
// Thread = 1 column. Step s: read halo rows (written step s-1) from slot p^1,
// update 8-deep partial-sum rings, compute this step's rows, write to slot p.
//   Wu(s) = by-6+4s+{0..3}   El(s) = by-12+4s+{0..3}
//   Eg(s) = by-18+4s+{0..3}  Eo(s) = by-24+4s+{0..3}  (stored for s>=6)
// __launch_bounds__(1024, 4): 16 waves/block = 4 waves/EU resident -> VGPR
// budget 512/4 = 128 (r9/r10 failed at the default 64-reg budget: spilled).
__global__ __launch_bounds__(1024, 4)
void pde_band(
    const float* __restrict__ Uin,
    const float* __restrict__ K1,
    const float* __restrict__ K2,
    const float* __restrict__ Aw,
    float* __restrict__ Uout)
{
    __shared__ float4 shU [2][WW];   // 128 KB total -> 1 block/CU (by design)
    __shared__ float4 shL0[2][WW];
    __shared__ float4 shL1[2][WW];
    __shared__ float4 shG [2][WW];

    const int c  = threadIdx.x;
    const int by = blockIdx.x * BH;
    const size_t plane = (size_t)blockIdx.y * (size_t)(HH * WW);
    const float* __restrict__ Ub = Uin + plane;
    float* __restrict__ Ob = Uout + plane;

    float w0[25], w1[25], aw[25];
#pragma unroll
    for (int t = 0; t < 25; ++t) { w0[t] = K1[t]; w1[t] = K1[25 + t]; aw[t] = Aw[t]; }
    const float k2a = K2[0], k2b = K2[1];

    const int cm2 = (c - 2) & (WW - 1), cm1 = (c - 1) & (WW - 1);
    const int cp1 = (c + 1) & (WW - 1), cp2 = (c + 2) & (WW - 1);

    // 8-deep partial-sum rings (all indices compile-static via parity unroll)
    float pL0[8], pL1[8], pG[8], pV[8];
#pragma unroll
    for (int i = 0; i < 8; ++i) { pL0[i]=0.f; pL1[i]=0.f; pG[i]=0.f; pV[i]=0.f; }

    float uC[4]  = {0,0,0,0};   // centers of u rows Wu(s-1)
    float lC0[4] = {0,0,0,0};
    float lC1[4] = {0,0,0,0};
    float gC[4]  = {0,0,0,0};

    const float4 z4 = {0.f, 0.f, 0.f, 0.f};
    shU[1][c] = z4; shL0[1][c] = z4; shL1[1][c] = z4; shG[1][c] = z4;  // slot read at s=0
    __syncthreads();

    for (int sb = 0; sb < NSTEP / 2; ++sb) {
#pragma unroll
      for (int p = 0; p < 2; ++p) {
        const int s   = 2 * sb + p;
        const int wsl = p;          // literal after unroll
        const int rsl = p ^ 1;

        // issue next-U global loads early (latency hides under FMA below)
        float uS[4];
#pragma unroll
        for (int q = 0; q < 4; ++q)
          uS[q] = Ub[(size_t)((unsigned)(by - 6 + 4*s + q) & (HH-1)) * WW + c];

        // identity rows only needed on emit steps (uniform branch)
        float idv[4] = {0.f, 0.f, 0.f, 0.f};
        if (s >= 6) {
#pragma unroll
          for (int q = 0; q < 4; ++q)
            idv[q] = Ub[(size_t)(by - 24 + 4*s + q) * WW + c];   // in [by, by+63]
        }

        // ---- u halo rows Wu(s-1) -> lam ring; compute El(s) ----
        float nl0[4], nl1[4];
        {
          float4 h0 = shU[rsl][cm2], h1 = shU[rsl][cm1];
          float4 h2 = shU[rsl][cp1], h3 = shU[rsl][cp2];
#pragma unroll
          for (int q = 0; q < 4; ++q) {
            const float uf[5] = {
              reinterpret_cast<const float*>(&h0)[q],
              reinterpret_cast<const float*>(&h1)[q],
              uC[q],
              reinterpret_cast<const float*>(&h2)[q],
              reinterpret_cast<const float*>(&h3)[q] };
#pragma unroll
            for (int t = 0; t < 5; ++t) {
              const int sl = (4*p + q + t + 4) & 7;
#pragma unroll
              for (int j = 0; j < 5; ++j) {
                pL0[sl] = fmaf(uf[j], w0[(4-t)*5 + j], pL0[sl]);
                pL1[sl] = fmaf(uf[j], w1[(4-t)*5 + j], pL1[sl]);
              }
            }
          }
#pragma unroll
          for (int k = 0; k < 4; ++k) {
            const int sl = (4*p + k + 4) & 7;
            nl0[k] = fmaxf(pL0[sl], 0.f) * k2a;  pL0[sl] = 0.f;
            nl1[k] = fmaxf(pL1[sl], 0.f) * k2b;  pL1[sl] = 0.f;
          }
        }

        // ---- lam halo rows El(s-1) -> grad ring (channel-SEQUENTIAL: fewer
        //      live halo temps -> lower register pressure) ----
        float ng[4];
        {
          {
            float4 a0 = shL0[rsl][cm2], a1 = shL0[rsl][cm1];
            float4 a2 = shL0[rsl][cp1], a3 = shL0[rsl][cp2];
#pragma unroll
            for (int q = 0; q < 4; ++q) {
              const float lf0[5] = {
                reinterpret_cast<const float*>(&a0)[q],
                reinterpret_cast<const float*>(&a1)[q],
                lC0[q],
                reinterpret_cast<const float*>(&a2)[q],
                reinterpret_cast<const float*>(&a3)[q] };
#pragma unroll
              for (int t = 0; t < 5; ++t) {
                const int sl = (4*p + q + t + 6) & 7;
#pragma unroll
                for (int j = 0; j < 5; ++j)
                  pG[sl] = fmaf(lf0[j], w0[t*5 + 4 - j], pG[sl]);  // K1^T: K1[ch][t][4-j]
              }
            }
          }
          {
            float4 b0 = shL1[rsl][cm2], b1 = shL1[rsl][cm1];
            float4 b2 = shL1[rsl][cp1], b3 = shL1[rsl][cp2];
#pragma unroll
            for (int q = 0; q < 4; ++q) {
              const float lf1[5] = {
                reinterpret_cast<const float*>(&b0)[q],
                reinterpret_cast<const float*>(&b1)[q],
                lC1[q],
                reinterpret_cast<const float*>(&b2)[q],
                reinterpret_cast<const float*>(&b3)[q] };
#pragma unroll
              for (int t = 0; t < 5; ++t) {
                const int sl = (4*p + q + t + 6) & 7;
#pragma unroll
                for (int j = 0; j < 5; ++j)
                  pG[sl] = fmaf(lf1[j], w1[t*5 + 4 - j], pG[sl]);
              }
            }
          }
#pragma unroll
          for (int k = 0; k < 4; ++k) {
            const int sl = (4*p + k + 6) & 7;
            ng[k] = pG[sl];  pG[sl] = 0.f;
          }
        }

        // ---- g halo rows Eg(s-1) -> vec ring; emit/store Eo(s) ----
        {
          float4 g0 = shG[rsl][cm2], g1 = shG[rsl][cm1];
          float4 g2 = shG[rsl][cp1], g3 = shG[rsl][cp2];
#pragma unroll
          for (int q = 0; q < 4; ++q) {
            const float gf[5] = {
              reinterpret_cast<const float*>(&g0)[q],
              reinterpret_cast<const float*>(&g1)[q],
              gC[q],
              reinterpret_cast<const float*>(&g2)[q],
              reinterpret_cast<const float*>(&g3)[q] };
#pragma unroll
            for (int t = 0; t < 5; ++t) {
              const int sl = (4*p + q + t) & 7;
#pragma unroll
              for (int j = 0; j < 5; ++j)
                pV[sl] = fmaf(gf[j], aw[(4-t)*5 + j], pV[sl]);
            }
          }
          if (s >= 6) {
#pragma unroll
            for (int k = 0; k < 4; ++k) {
              const int sl = (4*p + k) & 7;
              const int row = by - 24 + 4*s + k;      // in [by, by+63]
              Ob[(size_t)row * WW + c] = idv[k] + DTC * pV[sl];
              pV[sl] = 0.f;
            }
          } else {
#pragma unroll
            for (int k = 0; k < 4; ++k) pV[(4*p + k) & 7] = 0.f;
          }
        }

        // write this step's rows to the write slot; one barrier publishes them
        shU [wsl][c] = make_float4(uS[0], uS[1], uS[2], uS[3]);
        shL0[wsl][c] = make_float4(nl0[0], nl0[1], nl0[2], nl0[3]);
        shL1[wsl][c] = make_float4(nl1[0], nl1[1], nl1[2], nl1[3]);
        shG [wsl][c] = make_float4(ng[0], ng[1], ng[2], ng[3]);

        __syncthreads();

#pragma unroll
        for (int q = 0; q < 4; ++q) {
          uC[q] = uS[q]; lC0[q] = nl0[q]; lC1[q] = nl1[q]; gC[q] = ng[q];
        }
      }
    }
}

extern "C" void kernel_launch(void* const* d_in, const int* in_sizes, int n_in,
                              void* d_out, int out_size, void* d_ws, size_t ws_size,
                              hipStream_t stream) {
    const float* U  = (const float*)d_in[0];
    const float* K1 = (const float*)d_in[1];
    const float* K2 = (const float*)d_in[2];
    const float* Aw = (const float*)d_in[3];
    float* out = (float*)d_out;
    float* ws  = (float*)d_ws;

    const int B = in_sizes[0] / (HH * WW);   // 16
    dim3 grid(HH / BH, B);                   // 16 bands x 16 images = 256 blocks

    // 3 Euler layers; ping-pong in -> out -> ws -> out
    pde_band<<<grid, 1024, 0, stream>>>(U,   K1, K2, Aw, out);
    pde_band<<<grid, 1024, 0, stream>>>(out, K1, K2, Aw, ws);
    pde_band<<<grid, 1024, 0, stream>>>(ws,  K1, K2, Aw, out);
}

// Round 12
// 450.491 us; speedup vs baseline: 2.6125x; 2.6125x over previous
//
#include <hip/hip_runtime.h>

#define HH 1024
#define WW 1024
#define BH 64
#define SW 256            // strip width (cols per block = threads)
#define EMIT0 6           // first valid col in strip
#define EMIT1 250         // one past last valid col (244 emitted)
#define NSTEP 22          // 6 pipeline-fill + 16 emit steps (4 rows each)
#define DTC (0.1f/3.0f)

// Strip-pipelined 4-row row-pipeline. Block = 256 threads = 256 cols (1 col/thread),
// 5 strips x 244 emitted cols cover 1024 (12-col apron, store-masked).
// Per step s: read halo cols of rows written at s-1 from slot p^1, update 8-deep
// partial-sum rings, compute 4 new rows per stage, write slot p. 1 barrier/step.
//   Wu(s) = by-6+4s+{0..3}   El(s) = by-12+4s+{0..3}
//   Eg(s) = by-18+4s+{0..3}  Eo(s) = by-24+4s+{0..3}  (stored for s>=6)
// 256-thread block + 1-arg launch_bounds: derived min-waves/EU = 1 -> compiler
// may allocate past 64 VGPRs (m97 precedent: 164) instead of spilling.
__global__ __launch_bounds__(256)
void pde_band(
    const float* __restrict__ Uin,
    const float* __restrict__ K1,
    const float* __restrict__ K2,
    const float* __restrict__ Aw,
    float* __restrict__ Uout)
{
    __shared__ float4 shU [2][SW];   // 8 KB each pair, 32 KB total -> 5 blocks/CU
    __shared__ float4 shL0[2][SW];
    __shared__ float4 shL1[2][SW];
    __shared__ float4 shG [2][SW];

    const int c  = threadIdx.x;
    const int sx = blockIdx.x;                  // strip 0..4
    const int by = blockIdx.y * BH;
    const size_t plane = (size_t)blockIdx.z * (size_t)(HH * WW);
    const float* __restrict__ Ub = Uin + plane;
    float* __restrict__ Ob = Uout + plane;

    const int sbase = 244 * sx - 6;
    const int gcol  = (sbase + c) & (WW - 1);   // wrapped load col
    const int ecol  = sbase + c;                // emit col
    const bool emitok = (c >= EMIT0) && (c < EMIT1) && (ecol < WW);

    float w0[25], w1[25], aw[25];
#pragma unroll
    for (int t = 0; t < 25; ++t) { w0[t] = K1[t]; w1[t] = K1[25 + t]; aw[t] = Aw[t]; }
    const float k2a = K2[0], k2b = K2[1];

    // strip-internal halo cols (wrap &255: garbage feeds only store-masked cols)
    const int cm2 = (c - 2) & (SW - 1), cm1 = (c - 1) & (SW - 1);
    const int cp1 = (c + 1) & (SW - 1), cp2 = (c + 2) & (SW - 1);

    // 8-deep partial-sum rings (indices compile-static via parity unroll)
    float pL0[8], pL1[8], pG[8], pV[8];
#pragma unroll
    for (int i = 0; i < 8; ++i) { pL0[i]=0.f; pL1[i]=0.f; pG[i]=0.f; pV[i]=0.f; }

    float uC[4]  = {0,0,0,0};   // centers of rows Wu(s-1)
    float lC0[4] = {0,0,0,0};
    float lC1[4] = {0,0,0,0};
    float gC[4]  = {0,0,0,0};

    const float4 z4 = {0.f, 0.f, 0.f, 0.f};
    shU[1][c] = z4; shL0[1][c] = z4; shL1[1][c] = z4; shG[1][c] = z4;  // slot read at s=0
    __syncthreads();

    for (int sb = 0; sb < NSTEP / 2; ++sb) {
#pragma unroll
      for (int p = 0; p < 2; ++p) {
        const int s   = 2 * sb + p;
        const int wsl = p;          // literal after unroll
        const int rsl = p ^ 1;

        // issue next-U global loads early (latency hides under FMA below)
        float uS[4];
#pragma unroll
        for (int q = 0; q < 4; ++q)
          uS[q] = Ub[(size_t)((unsigned)(by - 6 + 4*s + q) & (HH-1)) * WW + gcol];

        float idv[4] = {0.f, 0.f, 0.f, 0.f};
        if (s >= 6) {
#pragma unroll
          for (int q = 0; q < 4; ++q)
            idv[q] = Ub[(size_t)(by - 24 + 4*s + q) * WW + gcol];   // rows in [by, by+63]
        }

        // ---- u halo rows Wu(s-1) -> lam ring; compute El(s) ----
        float nl0[4], nl1[4];
        {
          float4 h0 = shU[rsl][cm2], h1 = shU[rsl][cm1];
          float4 h2 = shU[rsl][cp1], h3 = shU[rsl][cp2];
#pragma unroll
          for (int q = 0; q < 4; ++q) {
            const float uf[5] = {
              reinterpret_cast<const float*>(&h0)[q],
              reinterpret_cast<const float*>(&h1)[q],
              uC[q],
              reinterpret_cast<const float*>(&h2)[q],
              reinterpret_cast<const float*>(&h3)[q] };
#pragma unroll
            for (int t = 0; t < 5; ++t) {
              const int sl = (4*p + q + t + 4) & 7;
#pragma unroll
              for (int j = 0; j < 5; ++j) {
                pL0[sl] = fmaf(uf[j], w0[(4-t)*5 + j], pL0[sl]);
                pL1[sl] = fmaf(uf[j], w1[(4-t)*5 + j], pL1[sl]);
              }
            }
          }
#pragma unroll
          for (int k = 0; k < 4; ++k) {
            const int sl = (4*p + k + 4) & 7;
            nl0[k] = fmaxf(pL0[sl], 0.f) * k2a;  pL0[sl] = 0.f;
            nl1[k] = fmaxf(pL1[sl], 0.f) * k2b;  pL1[sl] = 0.f;
          }
        }

        // ---- lam halo rows El(s-1) -> grad ring (channel-sequential) ----
        float ng[4];
        {
          {
            float4 a0 = shL0[rsl][cm2], a1 = shL0[rsl][cm1];
            float4 a2 = shL0[rsl][cp1], a3 = shL0[rsl][cp2];
#pragma unroll
            for (int q = 0; q < 4; ++q) {
              const float lf0[5] = {
                reinterpret_cast<const float*>(&a0)[q],
                reinterpret_cast<const float*>(&a1)[q],
                lC0[q],
                reinterpret_cast<const float*>(&a2)[q],
                reinterpret_cast<const float*>(&a3)[q] };
#pragma unroll
              for (int t = 0; t < 5; ++t) {
                const int sl = (4*p + q + t + 6) & 7;
#pragma unroll
                for (int j = 0; j < 5; ++j)
                  pG[sl] = fmaf(lf0[j], w0[t*5 + 4 - j], pG[sl]);  // K1^T: K1[ch][t][4-j]
              }
            }
          }
          {
            float4 b0 = shL1[rsl][cm2], b1 = shL1[rsl][cm1];
            float4 b2 = shL1[rsl][cp1], b3 = shL1[rsl][cp2];
#pragma unroll
            for (int q = 0; q < 4; ++q) {
              const float lf1[5] = {
                reinterpret_cast<const float*>(&b0)[q],
                reinterpret_cast<const float*>(&b1)[q],
                lC1[q],
                reinterpret_cast<const float*>(&b2)[q],
                reinterpret_cast<const float*>(&b3)[q] };
#pragma unroll
              for (int t = 0; t < 5; ++t) {
                const int sl = (4*p + q + t + 6) & 7;
#pragma unroll
                for (int j = 0; j < 5; ++j)
                  pG[sl] = fmaf(lf1[j], w1[t*5 + 4 - j], pG[sl]);
              }
            }
          }
#pragma unroll
          for (int k = 0; k < 4; ++k) {
            const int sl = (4*p + k + 6) & 7;
            ng[k] = pG[sl];  pG[sl] = 0.f;
          }
        }

        // ---- g halo rows Eg(s-1) -> vec ring; emit/store Eo(s) ----
        {
          float4 g0 = shG[rsl][cm2], g1 = shG[rsl][cm1];
          float4 g2 = shG[rsl][cp1], g3 = shG[rsl][cp2];
#pragma unroll
          for (int q = 0; q < 4; ++q) {
            const float gf[5] = {
              reinterpret_cast<const float*>(&g0)[q],
              reinterpret_cast<const float*>(&g1)[q],
              gC[q],
              reinterpret_cast<const float*>(&g2)[q],
              reinterpret_cast<const float*>(&g3)[q] };
#pragma unroll
            for (int t = 0; t < 5; ++t) {
              const int sl = (4*p + q + t) & 7;
#pragma unroll
              for (int j = 0; j < 5; ++j)
                pV[sl] = fmaf(gf[j], aw[(4-t)*5 + j], pV[sl]);
            }
          }
          if (s >= 6) {
#pragma unroll
            for (int k = 0; k < 4; ++k) {
              const int sl = (4*p + k) & 7;
              if (emitok) {
                const int row = by - 24 + 4*s + k;      // in [by, by+63]
                Ob[(size_t)row * WW + ecol] = idv[k] + DTC * pV[sl];
              }
              pV[sl] = 0.f;
            }
          } else {
#pragma unroll
            for (int k = 0; k < 4; ++k) pV[(4*p + k) & 7] = 0.f;
          }
        }

        // write this step's rows; one barrier publishes them
        shU [wsl][c] = make_float4(uS[0], uS[1], uS[2], uS[3]);
        shL0[wsl][c] = make_float4(nl0[0], nl0[1], nl0[2], nl0[3]);
        shL1[wsl][c] = make_float4(nl1[0], nl1[1], nl1[2], nl1[3]);
        shG [wsl][c] = make_float4(ng[0], ng[1], ng[2], ng[3]);

        __syncthreads();

#pragma unroll
        for (int q = 0; q < 4; ++q) {
          uC[q] = uS[q]; lC0[q] = nl0[q]; lC1[q] = nl1[q]; gC[q] = ng[q];
        }
      }
    }
}

extern "C" void kernel_launch(void* const* d_in, const int* in_sizes, int n_in,
                              void* d_out, int out_size, void* d_ws, size_t ws_size,
                              hipStream_t stream) {
    const float* U  = (const float*)d_in[0];
    const float* K1 = (const float*)d_in[1];
    const float* K2 = (const float*)d_in[2];
    const float* Aw = (const float*)d_in[3];
    float* out = (float*)d_out;
    float* ws  = (float*)d_ws;

    const int B = in_sizes[0] / (HH * WW);   // 16
    dim3 grid(5, HH / BH, B);                // 5 strips x 16 bands x 16 images = 1280 blocks

    // 3 Euler layers; ping-pong in -> out -> ws -> out
    pde_band<<<grid, 256, 0, stream>>>(U,   K1, K2, Aw, out);
    pde_band<<<grid, 256, 0, stream>>>(out, K1, K2, Aw, ws);
    pde_band<<<grid, 256, 0, stream>>>(ws,  K1, K2, Aw, out);
}